// Round 12
// baseline (231.214 us; speedup 1.0000x reference)
//
#include <hip/hip_runtime.h>
#include <hip/hip_bf16.h>
#include <string.h>

#define Bsz 2
#define Tsz 2048
#define Dsz 1024
#define NHsz 16
#define Msz (Bsz*Tsz)  // 4096 rows total

typedef unsigned short bfu;  // bf16 bit pattern
typedef __attribute__((ext_vector_type(8))) short short8;   // MFMA A/B frag: 8 bf16
typedef __attribute__((ext_vector_type(4))) short short4v;
typedef __attribute__((ext_vector_type(4))) float floatx4;  // 16x16 MFMA C/D frag
typedef __attribute__((ext_vector_type(16))) float floatx16; // 32x32 MFMA C/D frag

__device__ __forceinline__ bfu f2bf(float f) {
  unsigned int u = __builtin_bit_cast(unsigned int, f);
  u += 0x7fffu + ((u >> 16) & 1u);
  return (bfu)(u >> 16);
}

__device__ __forceinline__ float fexp2(float x) {
#if __has_builtin(__builtin_amdgcn_exp2f)
  return __builtin_amdgcn_exp2f(x);   // raw v_exp_f32 (no libm range fixup)
#else
  return exp2f(x);
#endif
}

__device__ __forceinline__ unsigned pkbf(float a, float b) {  // v_cvt_pk_bf16_f32
  __hip_bfloat162 t = __float22bfloat162_rn(make_float2(a, b));
  unsigned u; memcpy(&u, &t, 4); return u;
}

__device__ __forceinline__ short4v pack4bf(float a, float b, float c_, float d) {
  uint2 uu; uu.x = pkbf(a, b); uu.y = pkbf(c_, d);
  return __builtin_bit_cast(short4v, uu);
}

__device__ __forceinline__ short8 pack8bf(float4 a, float4 b) {
  uint4 u;
  u.x = pkbf(a.x, a.y); u.y = pkbf(a.z, a.w);
  u.z = pkbf(b.x, b.y); u.w = pkbf(b.z, b.w);
  return __builtin_bit_cast(short8, u);
}

__device__ __forceinline__ void async16(const void* g, void* l) {
  void* gnc = (void*)g;
  __builtin_amdgcn_global_load_lds((__attribute__((address_space(1))) void*)gnc,
                                   (__attribute__((address_space(3))) void*)l,
                                   16, 0, 0);
}

// ------- W (KxN fp32) -> WT (NxK bf16), z=0..3; z==4: x fp32 -> bf16 -------
// z==0 (Wq) pre-scaled by log2e/sqrt(DH) so the GEMM epilogue needs no scale.
__global__ __launch_bounds__(256) void transpose_w(const float* __restrict__ W0, const float* __restrict__ W1,
                                                   const float* __restrict__ W2, const float* __restrict__ W3,
                                                   bfu* __restrict__ wt,
                                                   const float* __restrict__ x, bfu* __restrict__ xb) {
  if (blockIdx.z == 4) {               // fused xcvt: 1024 blocks x 256 thr x 16 elems
    const int bf = (int)blockIdx.y * 32 + (int)blockIdx.x;
    const size_t i = ((size_t)bf * 256 + threadIdx.y * 32 + threadIdx.x) * 16;
    float4 a0 = *(const float4*)(x + i),     a1 = *(const float4*)(x + i + 4);
    float4 b0 = *(const float4*)(x + i + 8), b1 = *(const float4*)(x + i + 12);
    *(short8*)(xb + i)     = pack8bf(a0, a1);
    *(short8*)(xb + i + 8) = pack8bf(b0, b1);
    return;
  }
  __shared__ float tile[32][33];
  const float* W = blockIdx.z == 0 ? W0 : blockIdx.z == 1 ? W1 : blockIdx.z == 2 ? W2 : W3;
  const float s = (blockIdx.z == 0) ? 0.18033688011112042f : 1.0f;  // 0.125*log2(e)
  bfu* WT = wt + (size_t)blockIdx.z * Dsz * Dsz;
  int tx = threadIdx.x, ty = threadIdx.y;           // 32 x 8
  int kb = blockIdx.y * 32, nb = blockIdx.x * 32;
#pragma unroll
  for (int i = 0; i < 4; ++i)
    tile[ty + i*8][tx] = W[(size_t)(kb + ty + i*8) * Dsz + nb + tx];
  __syncthreads();
#pragma unroll
  for (int i = 0; i < 4; ++i)
    WT[(size_t)(nb + ty + i*8) * Dsz + kb + tx] = f2bf(tile[tx][ty + i*8] * s);
}

// ---------------- 128xNT bf16 MFMA GEMM: C = A(MxK) * BT(NxK)^T ----------------
// 3-buffer pipeline (T3/T4): TWO stages in flight, counted vmcnt (never 0
// mid-loop). XOR-swizzled LDS (both sides).
// z==2 (NT=128, bf16 out): V written transposed VT[b][h][d][t] via LDS epilogue.
template <bool F32OUT, int NT>
__global__ __launch_bounds__(256) void gemm128(const bfu* __restrict__ Ain, const bfu* __restrict__ Bt0,
                                               void* __restrict__ C0, int K, int N,
                                               size_t strideB, size_t strideC) {
  constexpr int NJ = NT / 32;                       // n-frags per wave
  constexpr int LPS = 2 + NT / 64;                  // per-wave loads per stage
  const int tid = threadIdx.x, wave = tid >> 6, lane = tid & 63;
  const int g = lane >> 4, c = lane & 15;
  const int m0 = blockIdx.y * 128, n0 = blockIdx.x * NT;
  const bfu* Bt = Bt0 + strideB * blockIdx.z;
  __shared__ bfu smem[3][4096 + NT * 32];           // 3-stage: As | Bs
  floatx4 acc[4][NJ] = {};
  const int srow = lane >> 2;
  const int scol = (((lane & 3) ^ ((lane >> 3) & 3)) << 3);
  const bfu* gB = Bt + (size_t)(n0 + srow) * K + scol;
  const bfu* gA = Ain + (size_t)(m0 + srow) * K + scol;
  const int wm = (wave >> 1) * 64, wn = (wave & 1) * (NT / 2);
  const int roct = (g ^ ((c >> 1) & 3)) << 3;

#define STAGE_G(buf, k0)                                                        \
  {                                                                             \
    _Pragma("unroll")                                                           \
    for (int cc = 0; cc < 2; ++cc) {                                            \
      const int chunk = wave * 2 + cc;                                          \
      async16(gA + (size_t)chunk * 16 * K + (k0), &smem[buf][chunk * 512]);     \
    }                                                                           \
    _Pragma("unroll")                                                           \
    for (int cc = 0; cc < NT / 64; ++cc) {                                      \
      const int chunk = wave * (NT / 64) + cc;                                  \
      async16(gB + (size_t)chunk * 16 * K + (k0), &smem[buf][4096 + chunk * 512]); \
    }                                                                           \
  }

  const int NK = K / 32;               // = 32 here
  STAGE_G(0, 0);                       // prologue: stages 0,1 in flight
  STAGE_G(1, 32);
  int buf = 0;
  for (int t = 0; t < NK; ++t) {
    if (t + 2 < NK) {
      const int nb = (buf + 2) >= 3 ? buf - 1 : buf + 2;
      STAGE_G(nb, (t + 2) * 32);       // issue 2-ahead (overlaps 2 compute phases)
      asm volatile("s_waitcnt vmcnt(%0)" :: "i"(2 * LPS) : "memory");  // t landed
    } else if (t + 1 < NK) {
      asm volatile("s_waitcnt vmcnt(%0)" :: "i"(LPS) : "memory");
    } else {
      asm volatile("s_waitcnt vmcnt(0)" ::: "memory");
    }
    __builtin_amdgcn_s_barrier();
    asm volatile("" ::: "memory");

    const bfu* AsC = &smem[buf][0];
    const bfu* BsC = &smem[buf][4096];
    short8 afr[4], bfr[NJ];
#pragma unroll
    for (int i = 0; i < 4; ++i) afr[i] = *(const short8*)&AsC[(wm + i*16 + c) * 32 + roct];
#pragma unroll
    for (int j = 0; j < NJ; ++j) bfr[j] = *(const short8*)&BsC[(wn + j*16 + c) * 32 + roct];
#pragma unroll
    for (int i = 0; i < 4; ++i)
#pragma unroll
      for (int j = 0; j < NJ; ++j)
        acc[i][j] = __builtin_amdgcn_mfma_f32_16x16x32_bf16(afr[i], bfr[j], acc[i][j], 0, 0, 0);

    asm volatile("" ::: "memory");
    __builtin_amdgcn_s_barrier();      // reads of smem[buf] done -> may overwrite
    asm volatile("" ::: "memory");
    buf = (buf + 1 >= 3) ? 0 : buf + 1;
  }
#undef STAGE_G

  const bool vtrans = (!F32OUT) && (NT == 128) && (blockIdx.z == 2);
  if (vtrans) {
    bfu* sm = &smem[0][0];
    bfu* vtp = (bfu*)C0 + (size_t)2 * strideC;
#pragma unroll
    for (int p = 0; p < 2; ++p) {
      __syncthreads();
      if ((wave & 1) == p) {
#pragma unroll
        for (int i = 0; i < 4; ++i)
#pragma unroll
          for (int j = 0; j < NJ; ++j) {
            const int nl = j*16 + c;
            const int mg = ((wm + i*16) >> 3) + (g >> 1);
            const int phys = nl * 128 + ((mg ^ (nl & 15)) << 3) + ((g & 1) << 2);
            *(short4v*)&sm[phys] = pack4bf(acc[i][j][0], acc[i][j][1],
                                           acc[i][j][2], acc[i][j][3]);
          }
      }
      __syncthreads();
      const int h_ = (n0 + p * 64) >> 6;
      bfu* dst = vtp + ((size_t)((m0 >> 11) * 16 + h_) * 64) * Tsz + (m0 & 2047);
#pragma unroll
      for (int s = 0; s < 4; ++s) {
        const int nl = s * 16 + (tid >> 4);
        const int me = (tid & 15) << 3;
        const int phys = nl * 128 + (((me >> 3) ^ (nl & 15)) << 3);
        *(short8*)&dst[(size_t)nl * Tsz + me] = *(const short8*)&sm[phys];
      }
    }
    return;
  }

#pragma unroll
  for (int i = 0; i < 4; ++i) {
#pragma unroll
    for (int j = 0; j < NJ; ++j) {
      const int m = m0 + wm + i*16 + g*4;
      const int n = n0 + wn + j*16 + c;
#pragma unroll
      for (int r = 0; r < 4; ++r) {
        float v = acc[i][j][r];
        if (F32OUT) ((float*)C0)[(size_t)(m + r) * N + n] = v;
        else        ((bfu*)C0)[strideC * blockIdx.z + (size_t)(m + r) * N + n] = f2bf(v);
      }
    }
  }
}

// -------- causal flash attention v12: 32x32 MFMA core + fp32 splitK2 --------
// Q,K natural [b*T+t][h*64+d]; V transposed VT[b][h][d][t]. Q pre-scaled.
// Core = v7's HW-verified 32x32 formulation (wave = 32 q-rows; QK^T 8 MFMA,
// PV 8 full-rate 32x32x16 MFMA per 64-key tile; P in regs via cvt_pk +
// shfl_xor(32) assembly). Output = v5's proven memory path (splitK x2,
// NORMALIZED fp32 partials + (m,l), merge_split) -- v7's regression was its
// fp16 x4 partial traffic, not the core.
// Geometry: 512-thr blocks (8 waves) cover 4 q-tiles (256 rows); sweeps
// {a, 7-a} -> 18 key-tiles/block constant. Grid 8x32 = 256 blocks = 2/CU
// x 8 waves = 16 waves/CU. Wave-uniform causal guard kt<=tq. Single-barrier
// loop (validated v11). XCD owns 4 heads (K/V 2MB in its L2).
__global__ __launch_bounds__(512, 4) void attn_kernel(const bfu* __restrict__ qkv,
                                                      float* __restrict__ op0,
                                                      float* __restrict__ op1,
                                                      float2* __restrict__ ml) {
  const int tid = threadIdx.x, wave = tid >> 6, lane = tid & 63;
  const int l31 = lane & 31, h = lane >> 5, l7 = lane & 7;

  // remap: bx = xcd (8); by: head-slot(1:0) | ks(2) | a0(4:3)
  const int xcd = (int)blockIdx.x, by = (int)blockIdx.y;
  const int s_ = by & 3, ks = (by >> 2) & 1, a0 = by >> 3;   // a0 = 0..3
  const int bh = xcd * 4 + s_;
  const int b = bh >> 4, hd = bh & 15;

  const size_t hbq = (size_t)b * Tsz * Dsz + hd * 64;
  const bfu* Qp = qkv + hbq;
  const bfu* Kp = qkv + (size_t)Msz * Dsz + hbq;
  const bfu* Vt = qkv + (size_t)2 * Msz * Dsz + (size_t)bh * 64 * Tsz;
  float* op = ks ? op1 : op0;

  __shared__ bfu Ks[2][64 * 64];      // [key][d], d-octets XOR (key&7)
  __shared__ bfu Vs[2][64 * 64];      // [d][key], key-octets XOR (d&7)

  const int srow8 = lane >> 3;                       // row within 8-row chunk
  const int soff = ((lane & 7) ^ srow8) << 3;        // pre-swizzled octet

  // loop-invariant LDS read offsets (elements)
  int kfo[2][4], vfo[4][2];
#pragma unroll
  for (int kh = 0; kh < 2; ++kh)
#pragma unroll
    for (int dc = 0; dc < 4; ++dc)
      kfo[kh][dc] = (kh*32 + l31)*64 + (((dc*2 + h) ^ l7) << 3);
#pragma unroll
  for (int s = 0; s < 4; ++s)
#pragma unroll
    for (int db = 0; db < 2; ++db)
      vfo[s][db] = (db*32 + l31)*64 + (((s*2 + h) ^ l7) << 3);

  for (int sw = 0; sw < 2; ++sw) {
    const int ae = sw ? (7 - a0) : a0;         // quad-group 0..7
    const int ktend = 4 * ae + 3;              // last key-tile any wave needs
    const int tq = 4 * ae + (wave >> 1);       // wave's q-tile (2 waves/tile)
    const int qw = tq * 64 + (wave & 1) * 32;  // wave's first q-row
    const int myq = qw + l31;                  // this lane's q-row

    short8 bq[4];                              // Q B-frags: k=d, n=q
#pragma unroll
    for (int dc = 0; dc < 4; ++dc)
      bq[dc] = *(const short8*)(Qp + (size_t)myq * Dsz + dc*16 + h*8);

    floatx16 acc0 = {}, acc1 = {};
    float mi = -3.0e38f, li = 0.0f;            // per-lane (q = l31, own 32 keys)

    const bfu* kpp = Kp + (size_t)(ks*64 + wave*8 + srow8) * Dsz + soff;
    const bfu* vpp = Vt + (size_t)(wave*8 + srow8) * Tsz + ks*64 + soff;

    // sweep-start barrier: prior sweep's LDS reads done before restaging buf0
    asm volatile("" ::: "memory");
    __builtin_amdgcn_s_barrier();
    asm volatile("" ::: "memory");
    async16(kpp, &Ks[0][wave * 512]);          // prologue: stage kt=ks
    async16(vpp, &Vs[0][wave * 512]);
    kpp += (size_t)128 * Dsz;                  // +2 key-tiles
    vpp += 128;

    int cur = 0;
    for (int kt = ks; kt <= ktend; kt += 2) {
      asm volatile("s_waitcnt vmcnt(0)" ::: "memory");  // aged loads (1 it. old)
      __builtin_amdgcn_s_barrier();
      asm volatile("" ::: "memory");

      if (kt + 2 <= ktend) {                   // prefetch kt+2 into cur^1
        async16(kpp, &Ks[cur ^ 1][wave * 512]);
        async16(vpp, &Vs[cur ^ 1][wave * 512]);
        kpp += (size_t)128 * Dsz;
        vpp += 128;
      }

      if (kt <= tq) {                          // wave-uniform causal guard
        const bfu* KsC = &Ks[cur][0];
        const bfu* VsC = &Vs[cur][0];

        // S^T via 32x32x16: A=K (m=key), B=Q (n=q)
        floatx16 st0 = {}, st1 = {};
        __builtin_amdgcn_s_setprio(1);
#pragma unroll
        for (int dc = 0; dc < 4; ++dc) {
          const short8 kf0 = *(const short8*)&KsC[kfo[0][dc]];
          st0 = __builtin_amdgcn_mfma_f32_32x32x16_bf16(kf0, bq[dc], st0, 0, 0, 0);
          const short8 kf1 = *(const short8*)&KsC[kfo[1][dc]];
          st1 = __builtin_amdgcn_mfma_f32_32x32x16_bf16(kf1, bq[dc], st1, 0, 0, 0);
        }
        __builtin_amdgcn_s_setprio(0);

        if (kt == tq) {                        // diagonal mask
#pragma unroll
          for (int r = 0; r < 16; ++r) {
            const int k0 = kt*64 + (r & 3) + 8*(r >> 2) + 4*h;
            if (k0 > myq)      st0[r] = -1.0e38f;
            if (k0 + 32 > myq) st1[r] = -1.0e38f;
          }
        }

        // online softmax (per-lane: q = l31, this lane's 32 keys)
        float mx[8];
#pragma unroll
        for (int i = 0; i < 8; ++i)
          mx[i] = fmaxf(fmaxf(st0[2*i], st0[2*i+1]), fmaxf(st1[2*i], st1[2*i+1]));
        float mloc = fmaxf(fmaxf(fmaxf(mx[0], mx[1]), fmaxf(mx[2], mx[3])),
                           fmaxf(fmaxf(mx[4], mx[5]), fmaxf(mx[6], mx[7])));
        const bool resc = !__all(mloc <= mi + 8.0f);   // defer-max (T13)
        if (resc) {
          const float mr = fmaxf(mloc, __shfl_xor(mloc, 32));  // per-q max
          const float mnew = fmaxf(mi, mr);
          const float alpha = fexp2(mi - mnew);
          li *= alpha; mi = mnew;
#pragma unroll
          for (int r = 0; r < 16; ++r) {
            const float al = __shfl(alpha, (r & 3) + 8*(r >> 2) + 4*h);
            acc0[r] *= al; acc1[r] *= al;
          }
        }
        float sum = 0.0f;
#pragma unroll
        for (int r = 0; r < 16; ++r) { st0[r] = fexp2(st0[r] - mi); sum += st0[r]; }
#pragma unroll
        for (int r = 0; r < 16; ++r) { st1[r] = fexp2(st1[r] - mi); sum += st1[r]; }
        li += sum;

        // P -> PV A-frags (keys s*16..+15), then O += P*V (32x32x16)
        __builtin_amdgcn_s_setprio(1);
#pragma unroll
        for (int s = 0; s < 4; ++s) {
          const int base = 8 * (s & 1);
          unsigned w0, w1, w2, w3;
          if (s < 2) {
            w0 = pkbf(st0[base],   st0[base+1]); w1 = pkbf(st0[base+2], st0[base+3]);
            w2 = pkbf(st0[base+4], st0[base+5]); w3 = pkbf(st0[base+6], st0[base+7]);
          } else {
            w0 = pkbf(st1[base],   st1[base+1]); w1 = pkbf(st1[base+2], st1[base+3]);
            w2 = pkbf(st1[base+4], st1[base+5]); w3 = pkbf(st1[base+6], st1[base+7]);
          }
          const unsigned w0x = (unsigned)__shfl_xor((int)w0, 32);
          const unsigned w1x = (unsigned)__shfl_xor((int)w1, 32);
          const unsigned w2x = (unsigned)__shfl_xor((int)w2, 32);
          const unsigned w3x = (unsigned)__shfl_xor((int)w3, 32);
          uint4 au;
          au.x = h ? w2x : w0;   // keys s*16 + h*8 + {0,1}
          au.y = h ? w3x : w1;   //                + {2,3}
          au.z = h ? w2  : w0x;  //                + {4,5}
          au.w = h ? w3  : w1x;  //                + {6,7}
          const short8 pa = __builtin_bit_cast(short8, au);
          const short8 vf0 = *(const short8*)&VsC[vfo[s][0]];
          acc0 = __builtin_amdgcn_mfma_f32_32x32x16_bf16(pa, vf0, acc0, 0, 0, 0);
          const short8 vf1 = *(const short8*)&VsC[vfo[s][1]];
          acc1 = __builtin_amdgcn_mfma_f32_32x32x16_bf16(pa, vf1, acc1, 0, 0, 0);
        }
        __builtin_amdgcn_s_setprio(0);
      }

      cur ^= 1;                        // no end barrier: next top barrier covers
    }

    // epilogue: per-q l = li + li(lane^32); write normalized fp32 partial
    const float lt = li + __shfl_xor(li, 32);
    const float invq = lt > 0.0f ? 1.0f / lt : 0.0f;
#pragma unroll
    for (int r = 0; r < 16; ++r) {
      const int qr = (r & 3) + 8*(r >> 2) + 4*h;
      const float iv = __shfl(invq, qr);
      const size_t rowo = (size_t)(b * Tsz + qw + qr) * Dsz + hd * 64 + l31;
      op[rowo]      = acc0[r] * iv;
      op[rowo + 32] = acc1[r] * iv;
    }
    if (lane < 32)
      ml[(size_t)ks * 65536 + bh * 2048 + qw + l31] = make_float2(mi, lt);
  }
}

// ---------------- merge the two split-K partials -> bf16 obuf ----------------
__global__ __launch_bounds__(256) void merge_split(const float* __restrict__ o0,
                                                   const float* __restrict__ o1,
                                                   const float2* __restrict__ ml,
                                                   bfu* __restrict__ ob) {
  const int idx = blockIdx.x * 256 + threadIdx.x;   // 524288 threads x 8 elems
  const int row = idx >> 7, ch = idx & 127;
  const int b = row >> 11, q = row & 2047;
  const int bh = b * 16 + (ch >> 3);
  const float2 a0 = ml[bh * 2048 + q];
  const float2 a1 = ml[65536 + bh * 2048 + q];
  const float M = fmaxf(a0.x, a1.x);
  const float w0 = fexp2(a0.x - M) * a0.y;
  const float w1 = fexp2(a1.x - M) * a1.y;
  const float inv = 1.0f / (w0 + w1);               // w0 > 0 always (kt=0 in split 0)
  const float u0 = w0 * inv, u1 = w1 * inv;
  const size_t off = (size_t)row * 1024 + ch * 8;
  float4 p0 = *(const float4*)(o0 + off), q0 = *(const float4*)(o0 + off + 4);
  float4 p1 = *(const float4*)(o1 + off), q1 = *(const float4*)(o1 + off + 4);
  float4 ra, rb;
  ra.x = u0*p0.x + u1*p1.x; ra.y = u0*p0.y + u1*p1.y;
  ra.z = u0*p0.z + u1*p1.z; ra.w = u0*p0.w + u1*p1.w;
  rb.x = u0*q0.x + u1*q1.x; rb.y = u0*q0.y + u1*q1.y;
  rb.z = u0*q0.z + u1*q1.z; rb.w = u0*q0.w + u1*q1.w;
  *(short8*)(ob + off) = pack8bf(ra, rb);
}

extern "C" void kernel_launch(void* const* d_in, const int* in_sizes, int n_in,
                              void* d_out, int out_size, void* d_ws, size_t ws_size,
                              hipStream_t stream) {
  const float* x  = (const float*)d_in[0];
  const float* Wq = (const float*)d_in[1];
  const float* Wk = (const float*)d_in[2];
  const float* Wv = (const float*)d_in[3];
  const float* Wo = (const float*)d_in[4];
  float* out = (float*)d_out;

  // workspace: wt 8MB | qkv 24MB | obuf 8MB (also xbf) | op0 16MB | op1 16MB | ml 1MB = 73 MiB
  bfu* wt    = (bfu*)d_ws;
  bfu* qkv   = wt + (size_t)4 * Dsz * Dsz;
  bfu* obuf  = qkv + (size_t)3 * Msz * Dsz;   // merged O; doubles as xbf (disjoint lifetime)
  float* op0 = (float*)(obuf + (size_t)Msz * Dsz);
  float* op1 = op0 + (size_t)Msz * Dsz;
  float2* ml = (float2*)(op1 + (size_t)Msz * Dsz);

  // weights transpose (z<4) + x->bf16 (z==4) in one launch
  transpose_w<<<dim3(32, 32, 5), dim3(32, 8), 0, stream>>>(Wq, Wk, Wv, Wo, wt, x, obuf);
  // QKV projections (pure-bf16 A path); Q scale folded into Wq; V -> VT (z==2)
  gemm128<false, 128><<<dim3(Dsz / 128, Msz / 128, 3), dim3(256), 0, stream>>>(
      obuf, wt, (void*)qkv, Dsz, Dsz, (size_t)Dsz * Dsz, (size_t)Msz * Dsz);
  attn_kernel<<<dim3(8, 32), dim3(512), 0, stream>>>(qkv, op0, op1, ml);
  merge_split<<<dim3(2048), dim3(256), 0, stream>>>(op0, op1, ml, obuf);
  // output projection -> fp32 d_out
  gemm128<true, 64><<<dim3(Dsz / 64, Msz / 128, 1), dim3(256), 0, stream>>>(
      obuf, wt + (size_t)3 * Dsz * Dsz, (void*)out, Dsz, Dsz,
      (size_t)0, (size_t)0);
}

// Round 13
// 185.830 us; speedup vs baseline: 1.2442x; 1.2442x over previous
//
#include <hip/hip_runtime.h>
#include <hip/hip_bf16.h>
#include <string.h>

#define Bsz 2
#define Tsz 2048
#define Dsz 1024
#define NHsz 16
#define Msz (Bsz*Tsz)  // 4096 rows total

typedef unsigned short bfu;  // bf16 bit pattern
typedef __attribute__((ext_vector_type(8))) short short8;   // MFMA A/B frag: 8 bf16
typedef __attribute__((ext_vector_type(4))) short short4v;
typedef __attribute__((ext_vector_type(4))) float floatx4;  // MFMA C/D frag

__device__ __forceinline__ bfu f2bf(float f) {
  unsigned int u = __builtin_bit_cast(unsigned int, f);
  u += 0x7fffu + ((u >> 16) & 1u);
  return (bfu)(u >> 16);
}

__device__ __forceinline__ float fexp2(float x) {
#if __has_builtin(__builtin_amdgcn_exp2f)
  return __builtin_amdgcn_exp2f(x);   // raw v_exp_f32 (no libm range fixup)
#else
  return exp2f(x);
#endif
}

__device__ __forceinline__ short4v pack4bf(float a, float b, float c_, float d) {
  __hip_bfloat162 h01 = __float22bfloat162_rn(make_float2(a, b));
  __hip_bfloat162 h23 = __float22bfloat162_rn(make_float2(c_, d));
  uint2 uu;
  memcpy(&uu.x, &h01, 4);
  memcpy(&uu.y, &h23, 4);
  return __builtin_bit_cast(short4v, uu);
}

__device__ __forceinline__ short8 pack8bf(float4 a, float4 b) {
  __hip_bfloat162 h0 = __float22bfloat162_rn(make_float2(a.x, a.y));
  __hip_bfloat162 h1 = __float22bfloat162_rn(make_float2(a.z, a.w));
  __hip_bfloat162 h2 = __float22bfloat162_rn(make_float2(b.x, b.y));
  __hip_bfloat162 h3 = __float22bfloat162_rn(make_float2(b.z, b.w));
  uint4 u;
  memcpy(&u.x, &h0, 4); memcpy(&u.y, &h1, 4);
  memcpy(&u.z, &h2, 4); memcpy(&u.w, &h3, 4);
  return __builtin_bit_cast(short8, u);
}

__device__ __forceinline__ void async16(const void* g, void* l) {
  void* gnc = (void*)g;
  __builtin_amdgcn_global_load_lds((__attribute__((address_space(1))) void*)gnc,
                                   (__attribute__((address_space(3))) void*)l,
                                   16, 0, 0);
}

// ------- W (KxN fp32) -> WT (NxK bf16), z=0..3; z==4: x fp32 -> bf16 -------
// z==0 (Wq) pre-scaled by log2e/sqrt(DH) so the GEMM epilogue needs no scale.
__global__ __launch_bounds__(256) void transpose_w(const float* __restrict__ W0, const float* __restrict__ W1,
                                                   const float* __restrict__ W2, const float* __restrict__ W3,
                                                   bfu* __restrict__ wt,
                                                   const float* __restrict__ x, bfu* __restrict__ xb) {
  if (blockIdx.z == 4) {               // fused xcvt: 1024 blocks x 256 thr x 16 elems
    const int bf = (int)blockIdx.y * 32 + (int)blockIdx.x;
    const size_t i = ((size_t)bf * 256 + threadIdx.y * 32 + threadIdx.x) * 16;
    float4 a0 = *(const float4*)(x + i),     a1 = *(const float4*)(x + i + 4);
    float4 b0 = *(const float4*)(x + i + 8), b1 = *(const float4*)(x + i + 12);
    *(short8*)(xb + i)     = pack8bf(a0, a1);
    *(short8*)(xb + i + 8) = pack8bf(b0, b1);
    return;
  }
  __shared__ float tile[32][33];
  const float* W = blockIdx.z == 0 ? W0 : blockIdx.z == 1 ? W1 : blockIdx.z == 2 ? W2 : W3;
  const float s = (blockIdx.z == 0) ? 0.18033688011112042f : 1.0f;  // 0.125*log2(e)
  bfu* WT = wt + (size_t)blockIdx.z * Dsz * Dsz;
  int tx = threadIdx.x, ty = threadIdx.y;           // 32 x 8
  int kb = blockIdx.y * 32, nb = blockIdx.x * 32;
#pragma unroll
  for (int i = 0; i < 4; ++i)
    tile[ty + i*8][tx] = W[(size_t)(kb + ty + i*8) * Dsz + nb + tx];
  __syncthreads();
#pragma unroll
  for (int i = 0; i < 4; ++i)
    WT[(size_t)(nb + ty + i*8) * Dsz + kb + tx] = f2bf(tile[tx][ty + i*8] * s);
}

// ---------------- 128xNT bf16 MFMA GEMM: C = A(MxK) * BT(NxK)^T ----------------
// 3-buffer pipeline (T3/T4): TWO stages in flight, counted vmcnt (never 0
// mid-loop). XOR-swizzled LDS (both sides).
// z==2 (NT=128, bf16 out): V written transposed VT[b][h][d][t] via LDS epilogue.
template <bool F32OUT, int NT>
__global__ __launch_bounds__(256) void gemm128(const bfu* __restrict__ Ain, const bfu* __restrict__ Bt0,
                                               void* __restrict__ C0, int K, int N,
                                               size_t strideB, size_t strideC) {
  constexpr int NJ = NT / 32;                       // n-frags per wave
  constexpr int LPS = 2 + NT / 64;                  // per-wave loads per stage
  const int tid = threadIdx.x, wave = tid >> 6, lane = tid & 63;
  const int g = lane >> 4, c = lane & 15;
  const int m0 = blockIdx.y * 128, n0 = blockIdx.x * NT;
  const bfu* Bt = Bt0 + strideB * blockIdx.z;
  __shared__ bfu smem[3][4096 + NT * 32];           // 3-stage: As | Bs
  floatx4 acc[4][NJ] = {};
  const int srow = lane >> 2;
  const int scol = (((lane & 3) ^ ((lane >> 3) & 3)) << 3);
  const bfu* gB = Bt + (size_t)(n0 + srow) * K + scol;
  const bfu* gA = Ain + (size_t)(m0 + srow) * K + scol;
  const int wm = (wave >> 1) * 64, wn = (wave & 1) * (NT / 2);
  const int roct = (g ^ ((c >> 1) & 3)) << 3;

#define STAGE_G(buf, k0)                                                        \
  {                                                                             \
    _Pragma("unroll")                                                           \
    for (int cc = 0; cc < 2; ++cc) {                                            \
      const int chunk = wave * 2 + cc;                                          \
      async16(gA + (size_t)chunk * 16 * K + (k0), &smem[buf][chunk * 512]);     \
    }                                                                           \
    _Pragma("unroll")                                                           \
    for (int cc = 0; cc < NT / 64; ++cc) {                                      \
      const int chunk = wave * (NT / 64) + cc;                                  \
      async16(gB + (size_t)chunk * 16 * K + (k0), &smem[buf][4096 + chunk * 512]); \
    }                                                                           \
  }

  const int NK = K / 32;               // = 32 here
  STAGE_G(0, 0);                       // prologue: stages 0,1 in flight
  STAGE_G(1, 32);
  int buf = 0;
  for (int t = 0; t < NK; ++t) {
    if (t + 2 < NK) {
      const int nb = (buf + 2) >= 3 ? buf - 1 : buf + 2;
      STAGE_G(nb, (t + 2) * 32);       // issue 2-ahead (overlaps 2 compute phases)
      asm volatile("s_waitcnt vmcnt(%0)" :: "i"(2 * LPS) : "memory");  // t landed
    } else if (t + 1 < NK) {
      asm volatile("s_waitcnt vmcnt(%0)" :: "i"(LPS) : "memory");
    } else {
      asm volatile("s_waitcnt vmcnt(0)" ::: "memory");
    }
    __builtin_amdgcn_s_barrier();
    asm volatile("" ::: "memory");

    const bfu* AsC = &smem[buf][0];
    const bfu* BsC = &smem[buf][4096];
    short8 afr[4], bfr[NJ];
#pragma unroll
    for (int i = 0; i < 4; ++i) afr[i] = *(const short8*)&AsC[(wm + i*16 + c) * 32 + roct];
#pragma unroll
    for (int j = 0; j < NJ; ++j) bfr[j] = *(const short8*)&BsC[(wn + j*16 + c) * 32 + roct];
#pragma unroll
    for (int i = 0; i < 4; ++i)
#pragma unroll
      for (int j = 0; j < NJ; ++j)
        acc[i][j] = __builtin_amdgcn_mfma_f32_16x16x32_bf16(afr[i], bfr[j], acc[i][j], 0, 0, 0);

    asm volatile("" ::: "memory");
    __builtin_amdgcn_s_barrier();      // reads of smem[buf] done -> may overwrite
    asm volatile("" ::: "memory");
    buf = (buf + 1 >= 3) ? 0 : buf + 1;
  }
#undef STAGE_G

  const bool vtrans = (!F32OUT) && (NT == 128) && (blockIdx.z == 2);
  if (vtrans) {
    bfu* sm = &smem[0][0];
    bfu* vtp = (bfu*)C0 + (size_t)2 * strideC;
#pragma unroll
    for (int p = 0; p < 2; ++p) {
      __syncthreads();
      if ((wave & 1) == p) {
#pragma unroll
        for (int i = 0; i < 4; ++i)
#pragma unroll
          for (int j = 0; j < NJ; ++j) {
            const int nl = j*16 + c;
            const int mg = ((wm + i*16) >> 3) + (g >> 1);
            const int phys = nl * 128 + ((mg ^ (nl & 15)) << 3) + ((g & 1) << 2);
            *(short4v*)&sm[phys] = pack4bf(acc[i][j][0], acc[i][j][1],
                                           acc[i][j][2], acc[i][j][3]);
          }
      }
      __syncthreads();
      const int h_ = (n0 + p * 64) >> 6;
      bfu* dst = vtp + ((size_t)((m0 >> 11) * 16 + h_) * 64) * Tsz + (m0 & 2047);
#pragma unroll
      for (int s = 0; s < 4; ++s) {
        const int nl = s * 16 + (tid >> 4);
        const int me = (tid & 15) << 3;
        const int phys = nl * 128 + (((me >> 3) ^ (nl & 15)) << 3);
        *(short8*)&dst[(size_t)nl * Tsz + me] = *(const short8*)&sm[phys];
      }
    }
    return;
  }

#pragma unroll
  for (int i = 0; i < 4; ++i) {
#pragma unroll
    for (int j = 0; j < NJ; ++j) {
      const int m = m0 + wm + i*16 + g*4;
      const int n = n0 + wn + j*16 + c;
#pragma unroll
      for (int r = 0; r < 4; ++r) {
        float v = acc[i][j][r];
        if (F32OUT) ((float*)C0)[(size_t)(m + r) * N + n] = v;
        else        ((bfu*)C0)[strideC * blockIdx.z + (size_t)(m + r) * N + n] = f2bf(v);
      }
    }
  }
}

// ---------------- causal flash attention (S^T formulation, v5: split-K x2) ---
// (verified best: 46.8 us, FETCH 12 MB, WRITE 34 MB, MfmaUtil ~21%)
__global__ __launch_bounds__(256, 4) void attn_kernel(const bfu* __restrict__ qkv,
                                                      float* __restrict__ op0,
                                                      float* __restrict__ op1,
                                                      float2* __restrict__ ml) {
  const int tid = threadIdx.x, wave = tid >> 6, lane = tid & 63;
  const int g = (lane >> 4) & 3, c = lane & 15, c7 = c & 7;

  // remap: flat(0..1023) -> xcd(2:0) | ksplit(3) | head-slot(5:4) | j0(9:6)
  const int flat = (int)blockIdx.y * 32 + (int)blockIdx.x;
  const int xcd = flat & 7, r_ = flat >> 3;
  const int ksplit = r_ & 1;
  const int s = (r_ >> 1) & 3, j0 = r_ >> 3;    // j0 = 0..15
  const int bh = xcd * 4 + s;
  const int b = bh >> 4, h = bh & 15;

  const size_t hbq = (size_t)b * Tsz * Dsz + h * 64;
  const bfu* Qp = qkv + hbq;
  const bfu* Kp = qkv + (size_t)Msz * Dsz + hbq;
  const bfu* Vt = qkv + (size_t)2 * Msz * Dsz + (size_t)bh * 64 * Tsz;
  float* op = ksplit ? op1 : op0;

  __shared__ bfu Ks[2][64 * 64];      // [key][d], d-octets XOR (key&7)
  __shared__ bfu Vs[2][64 * 64];      // [d][key], key-octets XOR (d&7)

  const int srow8 = lane >> 3;                       // row within chunk (0..7)
  const int soff = ((lane & 7) ^ srow8) << 3;        // swizzled octet offset
  const floatx4 z4 = {0.0f, 0.0f, 0.0f, 0.0f};

  for (int hf = 0; hf < 2; ++hf) {
    const int j = hf ? (31 - j0) : j0;               // q-tile index 0..31
    const int qw = j * 64 + wave * 16;

    short8 bq[2];                      // Q B-frags: n=q=qw+c, k=d
#pragma unroll
    for (int kk = 0; kk < 2; ++kk)
      bq[kk] = *(const short8*)(Qp + (size_t)(qw + c) * Dsz + kk * 32 + g * 8);

    floatx4 acc[4] = {};               // O: rows q=4g+r, cols d=nd*16+c
    float mi = -3.0e38f, li = 0.0f;    // li = PARTIAL sum (this lane's keys only)

    if (ksplit <= j) {
      const bfu* kpp[2]; const bfu* vpp[2];
#pragma unroll
      for (int cc = 0; cc < 2; ++cc) {
        const int ch = wave * 2 + cc;
        kpp[cc] = Kp + (size_t)(ksplit * 64 + ch * 8 + srow8) * Dsz + soff;  // K rows (keys)
        vpp[cc] = Vt + (size_t)(ch * 8 + srow8) * Tsz + ksplit * 64 + soff;  // V rows (d)
      }

      // prologue: stage kt=ksplit into buf 0
#pragma unroll
      for (int cc = 0; cc < 2; ++cc) {
        const int ch = wave * 2 + cc;
        async16(kpp[cc], &Ks[0][ch * 512]);
        async16(vpp[cc], &Vs[0][ch * 512]);
        kpp[cc] += (size_t)128 * Dsz;   // +2 key-tiles
        vpp[cc] += 128;
      }

      int cur = 0;
      for (int kt = ksplit; kt <= j; kt += 2) {
        if (kt + 2 <= j) {             // prefetch kt+2 into other buffer
#pragma unroll
          for (int cc = 0; cc < 2; ++cc) {
            const int ch = wave * 2 + cc;
            async16(kpp[cc], &Ks[cur ^ 1][ch * 512]);
            async16(vpp[cc], &Vs[cur ^ 1][ch * 512]);
            kpp[cc] += (size_t)128 * Dsz;
            vpp[cc] += 128;
          }
          asm volatile("s_waitcnt vmcnt(4)" ::: "memory");  // cur's 4 landed
        } else {
          asm volatile("s_waitcnt vmcnt(0)" ::: "memory");
        }
        __builtin_amdgcn_s_barrier();
        asm volatile("" ::: "memory");

        const bfu* KsC = &Ks[cur][0];
        const bfu* VsC = &Vs[cur][0];

        // S^T[key][q] = K * Q^T
        floatx4 st[4];
        __builtin_amdgcn_s_setprio(1);
#pragma unroll
        for (int mk = 0; mk < 4; ++mk) {
          const short8 kf = *(const short8*)&KsC[(mk * 16 + c) * 64 + ((g ^ c7) << 3)];
          st[mk] = __builtin_amdgcn_mfma_f32_16x16x32_bf16(kf, bq[0], z4, 0, 0, 0);
        }
#pragma unroll
        for (int mk = 0; mk < 4; ++mk) {
          const short8 kf = *(const short8*)&KsC[(mk * 16 + c) * 64 + (((4 + g) ^ c7) << 3)];
          st[mk] = __builtin_amdgcn_mfma_f32_16x16x32_bf16(kf, bq[1], st[mk], 0, 0, 0);
        }
        __builtin_amdgcn_s_setprio(0);

        if (kt == j) {                 // causal mask (diagonal tile only)
#pragma unroll
          for (int mk = 0; mk < 4; ++mk) {
            const int keyb = kt * 64 + mk * 16 + g * 4;
#pragma unroll
            for (int r = 0; r < 4; ++r)
              if (keyb + r > qw + c) st[mk][r] = -1.0e38f;
          }
        }

        // online softmax, no cross-lane on common path (partial li)
        float mloc = -3.0e38f;
#pragma unroll
        for (int mk = 0; mk < 4; ++mk)
          mloc = fmaxf(mloc, fmaxf(fmaxf(st[mk][0], st[mk][1]),
                                   fmaxf(st[mk][2], st[mk][3])));
        const bool resc = !__all(mloc <= mi + 8.0f);  // defer-max (T13)
        if (resc) {                    // rare: full reduce + rescale
          float mr = fmaxf(mloc, __shfl_xor(mloc, 16));
          mr = fmaxf(mr, __shfl_xor(mr, 32));
          const float mnew = fmaxf(mi, mr);
          const float alpha = fexp2(mi - mnew);
          li *= alpha;
          mi = mnew;
          float al[4];
#pragma unroll
          for (int rr = 0; rr < 4; ++rr) al[rr] = __shfl(alpha, (lane & 48) | (g * 4 + rr));
#pragma unroll
          for (int nd = 0; nd < 4; ++nd)
#pragma unroll
            for (int rr = 0; rr < 4; ++rr) acc[nd][rr] *= al[rr];
        }
        short4v pa[4];                 // P as K=16 A-frags, in regs
#pragma unroll
        for (int mk = 0; mk < 4; ++mk) {
          const float p0 = fexp2(st[mk][0] - mi);
          const float p1 = fexp2(st[mk][1] - mi);
          const float p2 = fexp2(st[mk][2] - mi);
          const float p3 = fexp2(st[mk][3] - mi);
          li += (p0 + p1) + (p2 + p3);
          pa[mk] = pack4bf(p0, p1, p2, p3);
        }

        // O += P * V via 16x16x16 (P in regs)
        __builtin_amdgcn_s_setprio(1);
#pragma unroll
        for (int mk = 0; mk < 4; ++mk)
#pragma unroll
          for (int nd = 0; nd < 4; ++nd) {
            const short4v vf = *(const short4v*)&VsC[(nd * 16 + c) * 64 +
                ((((mk << 1) + (g >> 1)) ^ c7) << 3) + ((g & 1) << 2)];
            acc[nd] = __builtin_amdgcn_mfma_f32_16x16x16bf16_1k(pa[mk], vf, acc[nd], 0, 0, 0);
          }
        __builtin_amdgcn_s_setprio(0);

        asm volatile("" ::: "memory");
        __builtin_amdgcn_s_barrier();  // all reads of buf[cur] done
        asm volatile("" ::: "memory");
        cur ^= 1;
      }
    }

    // reduce the 4 g-replica partial sums once; write fp32 partial O + (m,l)
    float lt = li;
    lt += __shfl_xor(lt, 16);
    lt += __shfl_xor(lt, 32);
#pragma unroll
    for (int rr = 0; rr < 4; ++rr) {
      const float lr = __shfl(lt, (lane & 48) | (g * 4 + rr));
      const float inv = lr > 0.0f ? 1.0f / lr : 0.0f;
#pragma unroll
      for (int nd = 0; nd < 4; ++nd)
        op[(size_t)(b * Tsz + qw + g * 4 + rr) * Dsz + h * 64 + nd * 16 + c] =
            acc[nd][rr] * inv;
    }
    if (lane < 16)                    // one writer per q-row (g==0 replica)
      ml[(size_t)ksplit * 65536 + bh * 2048 + qw + c] = make_float2(mi, lt);
  }
}

// ---------------- merge the two split-K partials -> bf16 obuf ----------------
__global__ __launch_bounds__(256) void merge_split(const float* __restrict__ o0,
                                                   const float* __restrict__ o1,
                                                   const float2* __restrict__ ml,
                                                   bfu* __restrict__ ob) {
  const int idx = blockIdx.x * 256 + threadIdx.x;   // 524288 threads x 8 elems
  const int row = idx >> 7, ch = idx & 127;
  const int b = row >> 11, q = row & 2047;
  const int bh = b * 16 + (ch >> 3);
  const float2 a0 = ml[bh * 2048 + q];
  const float2 a1 = ml[65536 + bh * 2048 + q];
  const float M = fmaxf(a0.x, a1.x);
  const float w0 = fexp2(a0.x - M) * a0.y;
  const float w1 = fexp2(a1.x - M) * a1.y;
  const float inv = 1.0f / (w0 + w1);               // w0 > 0 always (kt=0 in split 0)
  const float u0 = w0 * inv, u1 = w1 * inv;
  const size_t off = (size_t)row * 1024 + ch * 8;
  float4 p0 = *(const float4*)(o0 + off), q0 = *(const float4*)(o0 + off + 4);
  float4 p1 = *(const float4*)(o1 + off), q1 = *(const float4*)(o1 + off + 4);
  float4 ra, rb;
  ra.x = u0*p0.x + u1*p1.x; ra.y = u0*p0.y + u1*p1.y;
  ra.z = u0*p0.z + u1*p1.z; ra.w = u0*p0.w + u1*p1.w;
  rb.x = u0*q0.x + u1*q1.x; rb.y = u0*q0.y + u1*q1.y;
  rb.z = u0*q0.z + u1*q1.z; rb.w = u0*q0.w + u1*q1.w;
  *(short8*)(ob + off) = pack8bf(ra, rb);
}

extern "C" void kernel_launch(void* const* d_in, const int* in_sizes, int n_in,
                              void* d_out, int out_size, void* d_ws, size_t ws_size,
                              hipStream_t stream) {
  const float* x  = (const float*)d_in[0];
  const float* Wq = (const float*)d_in[1];
  const float* Wk = (const float*)d_in[2];
  const float* Wv = (const float*)d_in[3];
  const float* Wo = (const float*)d_in[4];
  float* out = (float*)d_out;

  // workspace: wt 8MB | qkv 24MB | obuf 8MB (also xbf) | op0 16MB | op1 16MB | ml 1MB = 73 MiB
  bfu* wt    = (bfu*)d_ws;
  bfu* qkv   = wt + (size_t)4 * Dsz * Dsz;
  bfu* obuf  = qkv + (size_t)3 * Msz * Dsz;   // merged O; doubles as xbf (disjoint lifetime)
  float* op0 = (float*)(obuf + (size_t)Msz * Dsz);
  float* op1 = op0 + (size_t)Msz * Dsz;
  float2* ml = (float2*)(op1 + (size_t)Msz * Dsz);

  // weights transpose (z<4) + x->bf16 (z==4) in one launch
  transpose_w<<<dim3(32, 32, 5), dim3(32, 8), 0, stream>>>(Wq, Wk, Wv, Wo, wt, x, obuf);
  // QKV projections (pure-bf16 A path); Q scale folded into Wq; V -> VT (z==2)
  gemm128<false, 128><<<dim3(Dsz / 128, Msz / 128, 3), dim3(256), 0, stream>>>(
      obuf, wt, (void*)qkv, Dsz, Dsz, (size_t)Dsz * Dsz, (size_t)Msz * Dsz);
  attn_kernel<<<dim3(32, 32), dim3(256), 0, stream>>>(qkv, op0, op1, ml);
  merge_split<<<dim3(2048), dim3(256), 0, stream>>>(op0, op1, ml, obuf);
  // output projection -> fp32 d_out
  gemm128<true, 64><<<dim3(Dsz / 64, Msz / 128, 1), dim3(256), 0, stream>>>(
      obuf, wt + (size_t)3 * Dsz * Dsz, (void*)out, Dsz, Dsz,
      (size_t)0, (size_t)0);
}

// Round 14
// 184.371 us; speedup vs baseline: 1.2541x; 1.0079x over previous
//
#include <hip/hip_runtime.h>
#include <hip/hip_bf16.h>
#include <string.h>

#define Bsz 2
#define Tsz 2048
#define Dsz 1024
#define NHsz 16
#define Msz (Bsz*Tsz)  // 4096 rows total

typedef unsigned short bfu;  // bf16 bit pattern
typedef __attribute__((ext_vector_type(8))) short short8;   // MFMA A/B frag: 8 bf16
typedef __attribute__((ext_vector_type(4))) short short4v;
typedef __attribute__((ext_vector_type(4))) float floatx4;  // MFMA C/D frag

__device__ __forceinline__ bfu f2bf(float f) {
  unsigned int u = __builtin_bit_cast(unsigned int, f);
  u += 0x7fffu + ((u >> 16) & 1u);
  return (bfu)(u >> 16);
}

__device__ __forceinline__ float fexp2(float x) {
#if __has_builtin(__builtin_amdgcn_exp2f)
  return __builtin_amdgcn_exp2f(x);   // raw v_exp_f32 (no libm range fixup)
#else
  return exp2f(x);
#endif
}

__device__ __forceinline__ short4v pack4bf(float a, float b, float c_, float d) {
  __hip_bfloat162 h01 = __float22bfloat162_rn(make_float2(a, b));
  __hip_bfloat162 h23 = __float22bfloat162_rn(make_float2(c_, d));
  uint2 uu;
  memcpy(&uu.x, &h01, 4);
  memcpy(&uu.y, &h23, 4);
  return __builtin_bit_cast(short4v, uu);
}

__device__ __forceinline__ short8 pack8bf(float4 a, float4 b) {
  __hip_bfloat162 h0 = __float22bfloat162_rn(make_float2(a.x, a.y));
  __hip_bfloat162 h1 = __float22bfloat162_rn(make_float2(a.z, a.w));
  __hip_bfloat162 h2 = __float22bfloat162_rn(make_float2(b.x, b.y));
  __hip_bfloat162 h3 = __float22bfloat162_rn(make_float2(b.z, b.w));
  uint4 u;
  memcpy(&u.x, &h0, 4); memcpy(&u.y, &h1, 4);
  memcpy(&u.z, &h2, 4); memcpy(&u.w, &h3, 4);
  return __builtin_bit_cast(short8, u);
}

__device__ __forceinline__ void async16(const void* g, void* l) {
  void* gnc = (void*)g;
  __builtin_amdgcn_global_load_lds((__attribute__((address_space(1))) void*)gnc,
                                   (__attribute__((address_space(3))) void*)l,
                                   16, 0, 0);
}

// ------- W (KxN fp32) -> WT (NxK bf16), z=0..3; z==4: x fp32 -> bf16 -------
// z==0 (Wq) pre-scaled by log2e/sqrt(DH) so the GEMM epilogue needs no scale.
__global__ __launch_bounds__(256) void transpose_w(const float* __restrict__ W0, const float* __restrict__ W1,
                                                   const float* __restrict__ W2, const float* __restrict__ W3,
                                                   bfu* __restrict__ wt,
                                                   const float* __restrict__ x, bfu* __restrict__ xb) {
  if (blockIdx.z == 4) {               // fused xcvt: 1024 blocks x 256 thr x 16 elems
    const int bf = (int)blockIdx.y * 32 + (int)blockIdx.x;
    const size_t i = ((size_t)bf * 256 + threadIdx.y * 32 + threadIdx.x) * 16;
    float4 a0 = *(const float4*)(x + i),     a1 = *(const float4*)(x + i + 4);
    float4 b0 = *(const float4*)(x + i + 8), b1 = *(const float4*)(x + i + 12);
    *(short8*)(xb + i)     = pack8bf(a0, a1);
    *(short8*)(xb + i + 8) = pack8bf(b0, b1);
    return;
  }
  __shared__ float tile[32][33];
  const float* W = blockIdx.z == 0 ? W0 : blockIdx.z == 1 ? W1 : blockIdx.z == 2 ? W2 : W3;
  const float s = (blockIdx.z == 0) ? 0.18033688011112042f : 1.0f;  // 0.125*log2(e)
  bfu* WT = wt + (size_t)blockIdx.z * Dsz * Dsz;
  int tx = threadIdx.x, ty = threadIdx.y;           // 32 x 8
  int kb = blockIdx.y * 32, nb = blockIdx.x * 32;
#pragma unroll
  for (int i = 0; i < 4; ++i)
    tile[ty + i*8][tx] = W[(size_t)(kb + ty + i*8) * Dsz + nb + tx];
  __syncthreads();
#pragma unroll
  for (int i = 0; i < 4; ++i)
    WT[(size_t)(nb + ty + i*8) * Dsz + kb + tx] = f2bf(tile[tx][ty + i*8] * s);
}

// -------- fused QKV GEMM: 128(M) x 64(N) of Q, K AND V per block ------------
// A-tile (x) staged ONCE and afr read ONCE per k-step, shared by 3 weights:
// 10 LDS reads / 24 MFMA per wave-iter (vs 16/4-frag structure's 2.0 ratio).
// grid (16,32) = 512 blocks = exactly 2/CU. 3-stage pipeline, counted vmcnt.
// V epilogue: LDS-coalesced transpose to VT[b][h][d][t] (n-tile = one head).
__global__ __launch_bounds__(256) void gemm_qkv(const bfu* __restrict__ Ain,
                                                const bfu* __restrict__ wt,
                                                bfu* __restrict__ out) {
  const int tid = threadIdx.x, wave = tid >> 6, lane = tid & 63;
  const int g = lane >> 4, c = lane & 15;
  const int m0 = blockIdx.y * 128, n0 = blockIdx.x * 64;
  __shared__ bfu smem[3][10240];       // A[128x32] | B0|B1|B2 [64x32] per stage
  floatx4 acc[3][4][2] = {};
  const int srow = lane >> 2;                                  // 4 lanes/row
  const int scol = (((lane & 3) ^ ((lane >> 3) & 3)) << 3);    // swizzled octet
  const bfu* gA = Ain + (size_t)(m0 + srow) * Dsz + scol;
  const bfu* gB0 = wt + (size_t)(n0 + srow) * Dsz + scol;
  const bfu* gB1 = gB0 + (size_t)Dsz * Dsz;
  const bfu* gB2 = gB1 + (size_t)Dsz * Dsz;
  const int wm = (wave >> 1) * 64, wn = (wave & 1) * 32;
  const int roct = (g ^ ((c >> 1) & 3)) << 3;

#define STAGE_Q(buf, k0)                                                        \
  {                                                                             \
    _Pragma("unroll")                                                           \
    for (int cc = 0; cc < 2; ++cc) {                                            \
      const int chunk = wave * 2 + cc;                                          \
      async16(gA + (size_t)chunk * 16 * Dsz + (k0), &smem[buf][chunk * 512]);   \
    }                                                                           \
    async16(gB0 + (size_t)wave * 16 * Dsz + (k0), &smem[buf][4096 + wave * 512]); \
    async16(gB1 + (size_t)wave * 16 * Dsz + (k0), &smem[buf][6144 + wave * 512]); \
    async16(gB2 + (size_t)wave * 16 * Dsz + (k0), &smem[buf][8192 + wave * 512]); \
  }

  const int NK = Dsz / 32;             // 32 k-iters; LPS = 5
  STAGE_Q(0, 0);                       // prologue: stages 0,1 in flight
  STAGE_Q(1, 32);
  int buf = 0;
  for (int t = 0; t < NK; ++t) {
    if (t + 2 < NK) {
      const int nb = (buf + 2) >= 3 ? buf - 1 : buf + 2;
      STAGE_Q(nb, (t + 2) * 32);       // issue 2-ahead
      asm volatile("s_waitcnt vmcnt(10)" ::: "memory");  // stage t landed
    } else if (t + 1 < NK) {
      asm volatile("s_waitcnt vmcnt(5)" ::: "memory");
    } else {
      asm volatile("s_waitcnt vmcnt(0)" ::: "memory");
    }
    __builtin_amdgcn_s_barrier();
    asm volatile("" ::: "memory");

    const bfu* S = &smem[buf][0];
    short8 afr[4], bfr[3][2];
#pragma unroll
    for (int i = 0; i < 4; ++i)
      afr[i] = *(const short8*)&S[(wm + i*16 + c) * 32 + roct];
#pragma unroll
    for (int z = 0; z < 3; ++z)
#pragma unroll
      for (int j = 0; j < 2; ++j)
        bfr[z][j] = *(const short8*)&S[4096 + z*2048 + (wn + j*16 + c) * 32 + roct];
#pragma unroll
    for (int z = 0; z < 3; ++z)
#pragma unroll
      for (int i = 0; i < 4; ++i)
#pragma unroll
        for (int j = 0; j < 2; ++j)
          acc[z][i][j] = __builtin_amdgcn_mfma_f32_16x16x32_bf16(afr[i], bfr[z][j],
                                                                 acc[z][i][j], 0, 0, 0);

    asm volatile("" ::: "memory");
    __builtin_amdgcn_s_barrier();      // reads of smem[buf] done -> may overwrite
    asm volatile("" ::: "memory");
    buf = (buf + 1 >= 3) ? 0 : buf + 1;
  }
#undef STAGE_Q

  // Q (z=0), K (z=1): natural [m][n] bf16
#pragma unroll
  for (int z = 0; z < 2; ++z)
#pragma unroll
    for (int i = 0; i < 4; ++i)
#pragma unroll
      for (int j = 0; j < 2; ++j) {
        const int m = m0 + wm + i*16 + g*4;
        const int n = n0 + wn + j*16 + c;
#pragma unroll
        for (int r = 0; r < 4; ++r)
          out[(size_t)z * Msz * Dsz + (size_t)(m + r) * Dsz + n] = f2bf(acc[z][i][j][r]);
      }

  // V (z=2): LDS-coalesced transpose -> VT[b][h][d][t]; n-tile = one head.
  __syncthreads();                     // all K-loop LDS activity complete
  bfu* sm = &smem[0][0];               // 16 KB scratch [d=64][m=128], swizzled
#pragma unroll
  for (int i = 0; i < 4; ++i)
#pragma unroll
    for (int j = 0; j < 2; ++j) {
      const int d = wn + j*16 + c;                      // 0..63
      const int mg = ((wm + i*16) >> 3) + (g >> 1);     // m-granule of 8
      const int phys = d * 128 + ((mg ^ (d & 15)) << 3) + ((g & 1) << 2);
      *(short4v*)&sm[phys] = pack4bf(acc[2][i][j][0], acc[2][i][j][1],
                                     acc[2][i][j][2], acc[2][i][j][3]);
    }
  __syncthreads();
  const int h_ = n0 >> 6;
  bfu* dst = out + (size_t)2 * Msz * Dsz +
             ((size_t)((m0 >> 11) * 16 + h_) * 64) * Tsz + (m0 & 2047);
#pragma unroll
  for (int s = 0; s < 4; ++s) {
    const int nl = s * 16 + (tid >> 4);                 // d row 0..63
    const int me = (tid & 15) << 3;                     // m 0..127
    const int phys = nl * 128 + (((me >> 3) ^ (nl & 15)) << 3);
    *(short8*)&dst[(size_t)nl * Tsz + me] = *(const short8*)&sm[phys];
  }
}

// ---------------- 128xNT bf16 MFMA GEMM: C = A(MxK) * BT(NxK)^T ----------------
// 3-buffer pipeline (T3/T4); XOR-swizzled LDS. Used for out-proj (NT=64, fp32).
template <bool F32OUT, int NT>
__global__ __launch_bounds__(256) void gemm128(const bfu* __restrict__ Ain, const bfu* __restrict__ Bt0,
                                               void* __restrict__ C0, int K, int N,
                                               size_t strideB, size_t strideC) {
  constexpr int NJ = NT / 32;                       // n-frags per wave
  constexpr int LPS = 2 + NT / 64;                  // per-wave loads per stage
  const int tid = threadIdx.x, wave = tid >> 6, lane = tid & 63;
  const int g = lane >> 4, c = lane & 15;
  const int m0 = blockIdx.y * 128, n0 = blockIdx.x * NT;
  const bfu* Bt = Bt0 + strideB * blockIdx.z;
  __shared__ bfu smem[3][4096 + NT * 32];           // 3-stage: As | Bs
  floatx4 acc[4][NJ] = {};
  const int srow = lane >> 2;
  const int scol = (((lane & 3) ^ ((lane >> 3) & 3)) << 3);
  const bfu* gB = Bt + (size_t)(n0 + srow) * K + scol;
  const bfu* gA = Ain + (size_t)(m0 + srow) * K + scol;
  const int wm = (wave >> 1) * 64, wn = (wave & 1) * (NT / 2);
  const int roct = (g ^ ((c >> 1) & 3)) << 3;

#define STAGE_G(buf, k0)                                                        \
  {                                                                             \
    _Pragma("unroll")                                                           \
    for (int cc = 0; cc < 2; ++cc) {                                            \
      const int chunk = wave * 2 + cc;                                          \
      async16(gA + (size_t)chunk * 16 * K + (k0), &smem[buf][chunk * 512]);     \
    }                                                                           \
    _Pragma("unroll")                                                           \
    for (int cc = 0; cc < NT / 64; ++cc) {                                      \
      const int chunk = wave * (NT / 64) + cc;                                  \
      async16(gB + (size_t)chunk * 16 * K + (k0), &smem[buf][4096 + chunk * 512]); \
    }                                                                           \
  }

  const int NK = K / 32;               // = 32 here
  STAGE_G(0, 0);                       // prologue: stages 0,1 in flight
  STAGE_G(1, 32);
  int buf = 0;
  for (int t = 0; t < NK; ++t) {
    if (t + 2 < NK) {
      const int nb = (buf + 2) >= 3 ? buf - 1 : buf + 2;
      STAGE_G(nb, (t + 2) * 32);       // issue 2-ahead (overlaps 2 compute phases)
      asm volatile("s_waitcnt vmcnt(%0)" :: "i"(2 * LPS) : "memory");  // t landed
    } else if (t + 1 < NK) {
      asm volatile("s_waitcnt vmcnt(%0)" :: "i"(LPS) : "memory");
    } else {
      asm volatile("s_waitcnt vmcnt(0)" ::: "memory");
    }
    __builtin_amdgcn_s_barrier();
    asm volatile("" ::: "memory");

    const bfu* AsC = &smem[buf][0];
    const bfu* BsC = &smem[buf][4096];
    short8 afr[4], bfr[NJ];
#pragma unroll
    for (int i = 0; i < 4; ++i) afr[i] = *(const short8*)&AsC[(wm + i*16 + c) * 32 + roct];
#pragma unroll
    for (int j = 0; j < NJ; ++j) bfr[j] = *(const short8*)&BsC[(wn + j*16 + c) * 32 + roct];
#pragma unroll
    for (int i = 0; i < 4; ++i)
#pragma unroll
      for (int j = 0; j < NJ; ++j)
        acc[i][j] = __builtin_amdgcn_mfma_f32_16x16x32_bf16(afr[i], bfr[j], acc[i][j], 0, 0, 0);

    asm volatile("" ::: "memory");
    __builtin_amdgcn_s_barrier();      // reads of smem[buf] done -> may overwrite
    asm volatile("" ::: "memory");
    buf = (buf + 1 >= 3) ? 0 : buf + 1;
  }
#undef STAGE_G

#pragma unroll
  for (int i = 0; i < 4; ++i) {
#pragma unroll
    for (int j = 0; j < NJ; ++j) {
      const int m = m0 + wm + i*16 + g*4;
      const int n = n0 + wn + j*16 + c;
#pragma unroll
      for (int r = 0; r < 4; ++r) {
        float v = acc[i][j][r];
        if (F32OUT) ((float*)C0)[(size_t)(m + r) * N + n] = v;
        else        ((bfu*)C0)[strideC * blockIdx.z + (size_t)(m + r) * N + n] = f2bf(v);
      }
    }
  }
}

// ---------------- causal flash attention (S^T formulation, v5: split-K x2) ---
// (verified best: 46.8 us, FETCH 12 MB, WRITE 34 MB, MfmaUtil ~21%)
__global__ __launch_bounds__(256, 4) void attn_kernel(const bfu* __restrict__ qkv,
                                                      float* __restrict__ op0,
                                                      float* __restrict__ op1,
                                                      float2* __restrict__ ml) {
  const int tid = threadIdx.x, wave = tid >> 6, lane = tid & 63;
  const int g = (lane >> 4) & 3, c = lane & 15, c7 = c & 7;

  // remap: flat(0..1023) -> xcd(2:0) | ksplit(3) | head-slot(5:4) | j0(9:6)
  const int flat = (int)blockIdx.y * 32 + (int)blockIdx.x;
  const int xcd = flat & 7, r_ = flat >> 3;
  const int ksplit = r_ & 1;
  const int s = (r_ >> 1) & 3, j0 = r_ >> 3;    // j0 = 0..15
  const int bh = xcd * 4 + s;
  const int b = bh >> 4, h = bh & 15;

  const size_t hbq = (size_t)b * Tsz * Dsz + h * 64;
  const bfu* Qp = qkv + hbq;
  const bfu* Kp = qkv + (size_t)Msz * Dsz + hbq;
  const bfu* Vt = qkv + (size_t)2 * Msz * Dsz + (size_t)bh * 64 * Tsz;
  float* op = ksplit ? op1 : op0;

  __shared__ bfu Ks[2][64 * 64];      // [key][d], d-octets XOR (key&7)
  __shared__ bfu Vs[2][64 * 64];      // [d][key], key-octets XOR (d&7)

  const int srow8 = lane >> 3;                       // row within chunk (0..7)
  const int soff = ((lane & 7) ^ srow8) << 3;        // swizzled octet offset
  const floatx4 z4 = {0.0f, 0.0f, 0.0f, 0.0f};

  for (int hf = 0; hf < 2; ++hf) {
    const int j = hf ? (31 - j0) : j0;               // q-tile index 0..31
    const int qw = j * 64 + wave * 16;

    short8 bq[2];                      // Q B-frags: n=q=qw+c, k=d
#pragma unroll
    for (int kk = 0; kk < 2; ++kk)
      bq[kk] = *(const short8*)(Qp + (size_t)(qw + c) * Dsz + kk * 32 + g * 8);

    floatx4 acc[4] = {};               // O: rows q=4g+r, cols d=nd*16+c
    float mi = -3.0e38f, li = 0.0f;    // li = PARTIAL sum (this lane's keys only)

    if (ksplit <= j) {
      const bfu* kpp[2]; const bfu* vpp[2];
#pragma unroll
      for (int cc = 0; cc < 2; ++cc) {
        const int ch = wave * 2 + cc;
        kpp[cc] = Kp + (size_t)(ksplit * 64 + ch * 8 + srow8) * Dsz + soff;  // K rows (keys)
        vpp[cc] = Vt + (size_t)(ch * 8 + srow8) * Tsz + ksplit * 64 + soff;  // V rows (d)
      }

      // prologue: stage kt=ksplit into buf 0
#pragma unroll
      for (int cc = 0; cc < 2; ++cc) {
        const int ch = wave * 2 + cc;
        async16(kpp[cc], &Ks[0][ch * 512]);
        async16(vpp[cc], &Vs[0][ch * 512]);
        kpp[cc] += (size_t)128 * Dsz;   // +2 key-tiles
        vpp[cc] += 128;
      }

      int cur = 0;
      for (int kt = ksplit; kt <= j; kt += 2) {
        if (kt + 2 <= j) {             // prefetch kt+2 into other buffer
#pragma unroll
          for (int cc = 0; cc < 2; ++cc) {
            const int ch = wave * 2 + cc;
            async16(kpp[cc], &Ks[cur ^ 1][ch * 512]);
            async16(vpp[cc], &Vs[cur ^ 1][ch * 512]);
            kpp[cc] += (size_t)128 * Dsz;
            vpp[cc] += 128;
          }
          asm volatile("s_waitcnt vmcnt(4)" ::: "memory");  // cur's 4 landed
        } else {
          asm volatile("s_waitcnt vmcnt(0)" ::: "memory");
        }
        __builtin_amdgcn_s_barrier();
        asm volatile("" ::: "memory");

        const bfu* KsC = &Ks[cur][0];
        const bfu* VsC = &Vs[cur][0];

        // S^T[key][q] = K * Q^T
        floatx4 st[4];
        __builtin_amdgcn_s_setprio(1);
#pragma unroll
        for (int mk = 0; mk < 4; ++mk) {
          const short8 kf = *(const short8*)&KsC[(mk * 16 + c) * 64 + ((g ^ c7) << 3)];
          st[mk] = __builtin_amdgcn_mfma_f32_16x16x32_bf16(kf, bq[0], z4, 0, 0, 0);
        }
#pragma unroll
        for (int mk = 0; mk < 4; ++mk) {
          const short8 kf = *(const short8*)&KsC[(mk * 16 + c) * 64 + (((4 + g) ^ c7) << 3)];
          st[mk] = __builtin_amdgcn_mfma_f32_16x16x32_bf16(kf, bq[1], st[mk], 0, 0, 0);
        }
        __builtin_amdgcn_s_setprio(0);

        if (kt == j) {                 // causal mask (diagonal tile only)
#pragma unroll
          for (int mk = 0; mk < 4; ++mk) {
            const int keyb = kt * 64 + mk * 16 + g * 4;
#pragma unroll
            for (int r = 0; r < 4; ++r)
              if (keyb + r > qw + c) st[mk][r] = -1.0e38f;
          }
        }

        // online softmax, no cross-lane on common path (partial li)
        float mloc = -3.0e38f;
#pragma unroll
        for (int mk = 0; mk < 4; ++mk)
          mloc = fmaxf(mloc, fmaxf(fmaxf(st[mk][0], st[mk][1]),
                                   fmaxf(st[mk][2], st[mk][3])));
        const bool resc = !__all(mloc <= mi + 8.0f);  // defer-max (T13)
        if (resc) {                    // rare: full reduce + rescale
          float mr = fmaxf(mloc, __shfl_xor(mloc, 16));
          mr = fmaxf(mr, __shfl_xor(mr, 32));
          const float mnew = fmaxf(mi, mr);
          const float alpha = fexp2(mi - mnew);
          li *= alpha;
          mi = mnew;
          float al[4];
#pragma unroll
          for (int rr = 0; rr < 4; ++rr) al[rr] = __shfl(alpha, (lane & 48) | (g * 4 + rr));
#pragma unroll
          for (int nd = 0; nd < 4; ++nd)
#pragma unroll
            for (int rr = 0; rr < 4; ++rr) acc[nd][rr] *= al[rr];
        }
        short4v pa[4];                 // P as K=16 A-frags, in regs
#pragma unroll
        for (int mk = 0; mk < 4; ++mk) {
          const float p0 = fexp2(st[mk][0] - mi);
          const float p1 = fexp2(st[mk][1] - mi);
          const float p2 = fexp2(st[mk][2] - mi);
          const float p3 = fexp2(st[mk][3] - mi);
          li += (p0 + p1) + (p2 + p3);
          pa[mk] = pack4bf(p0, p1, p2, p3);
        }

        // O += P * V via 16x16x16 (P in regs)
        __builtin_amdgcn_s_setprio(1);
#pragma unroll
        for (int mk = 0; mk < 4; ++mk)
#pragma unroll
          for (int nd = 0; nd < 4; ++nd) {
            const short4v vf = *(const short4v*)&VsC[(nd * 16 + c) * 64 +
                ((((mk << 1) + (g >> 1)) ^ c7) << 3) + ((g & 1) << 2)];
            acc[nd] = __builtin_amdgcn_mfma_f32_16x16x16bf16_1k(pa[mk], vf, acc[nd], 0, 0, 0);
          }
        __builtin_amdgcn_s_setprio(0);

        asm volatile("" ::: "memory");
        __builtin_amdgcn_s_barrier();  // all reads of buf[cur] done
        asm volatile("" ::: "memory");
        cur ^= 1;
      }
    }

    // reduce the 4 g-replica partial sums once; write fp32 partial O + (m,l)
    float lt = li;
    lt += __shfl_xor(lt, 16);
    lt += __shfl_xor(lt, 32);
#pragma unroll
    for (int rr = 0; rr < 4; ++rr) {
      const float lr = __shfl(lt, (lane & 48) | (g * 4 + rr));
      const float inv = lr > 0.0f ? 1.0f / lr : 0.0f;
#pragma unroll
      for (int nd = 0; nd < 4; ++nd)
        op[(size_t)(b * Tsz + qw + g * 4 + rr) * Dsz + h * 64 + nd * 16 + c] =
            acc[nd][rr] * inv;
    }
    if (lane < 16)                    // one writer per q-row (g==0 replica)
      ml[(size_t)ksplit * 65536 + bh * 2048 + qw + c] = make_float2(mi, lt);
  }
}

// ---------------- merge the two split-K partials -> bf16 obuf ----------------
__global__ __launch_bounds__(256) void merge_split(const float* __restrict__ o0,
                                                   const float* __restrict__ o1,
                                                   const float2* __restrict__ ml,
                                                   bfu* __restrict__ ob) {
  const int idx = blockIdx.x * 256 + threadIdx.x;   // 524288 threads x 8 elems
  const int row = idx >> 7, ch = idx & 127;
  const int b = row >> 11, q = row & 2047;
  const int bh = b * 16 + (ch >> 3);
  const float2 a0 = ml[bh * 2048 + q];
  const float2 a1 = ml[65536 + bh * 2048 + q];
  const float M = fmaxf(a0.x, a1.x);
  const float w0 = fexp2(a0.x - M) * a0.y;
  const float w1 = fexp2(a1.x - M) * a1.y;
  const float inv = 1.0f / (w0 + w1);               // w0 > 0 always (kt=0 in split 0)
  const float u0 = w0 * inv, u1 = w1 * inv;
  const size_t off = (size_t)row * 1024 + ch * 8;
  float4 p0 = *(const float4*)(o0 + off), q0 = *(const float4*)(o0 + off + 4);
  float4 p1 = *(const float4*)(o1 + off), q1 = *(const float4*)(o1 + off + 4);
  float4 ra, rb;
  ra.x = u0*p0.x + u1*p1.x; ra.y = u0*p0.y + u1*p1.y;
  ra.z = u0*p0.z + u1*p1.z; ra.w = u0*p0.w + u1*p1.w;
  rb.x = u0*q0.x + u1*q1.x; rb.y = u0*q0.y + u1*q1.y;
  rb.z = u0*q0.z + u1*q1.z; rb.w = u0*q0.w + u1*q1.w;
  *(short8*)(ob + off) = pack8bf(ra, rb);
}

extern "C" void kernel_launch(void* const* d_in, const int* in_sizes, int n_in,
                              void* d_out, int out_size, void* d_ws, size_t ws_size,
                              hipStream_t stream) {
  const float* x  = (const float*)d_in[0];
  const float* Wq = (const float*)d_in[1];
  const float* Wk = (const float*)d_in[2];
  const float* Wv = (const float*)d_in[3];
  const float* Wo = (const float*)d_in[4];
  float* out = (float*)d_out;

  // workspace: wt 8MB | qkv 24MB | obuf 8MB (also xbf) | op0 16MB | op1 16MB | ml 1MB = 73 MiB
  bfu* wt    = (bfu*)d_ws;
  bfu* qkv   = wt + (size_t)4 * Dsz * Dsz;
  bfu* obuf  = qkv + (size_t)3 * Msz * Dsz;   // merged O; doubles as xbf (disjoint lifetime)
  float* op0 = (float*)(obuf + (size_t)Msz * Dsz);
  float* op1 = op0 + (size_t)Msz * Dsz;
  float2* ml = (float2*)(op1 + (size_t)Msz * Dsz);

  // weights transpose (z<4) + x->bf16 (z==4) in one launch
  transpose_w<<<dim3(32, 32, 5), dim3(32, 8), 0, stream>>>(Wq, Wk, Wv, Wo, wt, x, obuf);
  // fused QKV projection: A staged/read once for 3 weights; V -> VT in-kernel
  gemm_qkv<<<dim3(16, 32), dim3(256), 0, stream>>>(obuf, wt, qkv);
  attn_kernel<<<dim3(32, 32), dim3(256), 0, stream>>>(qkv, op0, op1, ml);
  merge_split<<<dim3(2048), dim3(256), 0, stream>>>(op0, op1, ml, obuf);
  // output projection -> fp32 d_out
  gemm128<true, 64><<<dim3(Dsz / 64, Msz / 128, 1), dim3(256), 0, stream>>>(
      obuf, wt + (size_t)3 * Dsz * Dsz, (void*)out, Dsz, Dsz,
      (size_t)0, (size_t)0);
}